// Round 9
// baseline (179.999 us; speedup 1.0000x reference)
//
#include <hip/hip_runtime.h>

typedef unsigned short u16;
typedef unsigned int   u32;
using bf16x8 = __bf16 __attribute__((ext_vector_type(8)));
using f32x4  = float  __attribute__((ext_vector_type(4)));
using f32x16 = float  __attribute__((ext_vector_type(16)));
using u32x2  = u32    __attribute__((ext_vector_type(2)));

#define B_    4
#define N_    2048
#define N2_   1024
#define DIM_  1024
#define H_    16
#define HD_   64
#define SCALE_ 0.125f
#define LOG2E_ 1.4426950408889634f

union PU { u32 w[4]; bf16x8 v; };

__device__ __forceinline__ u16 f2bf(float f) {
  unsigned u = __float_as_uint(f);
  u += 0x7fffu + ((u >> 16) & 1u);   // round-to-nearest-even
  return (u16)(u >> 16);
}

// compiler-generated bf16 pack (RNE) — layout-safe
__device__ __forceinline__ u32 packbf(float lo, float hi) {
  union { __bf16 b[2]; u32 u; } c;
  c.b[0] = (__bf16)lo; c.b[1] = (__bf16)hi;
  return c.u;
}

__device__ __forceinline__ float pair_max(float x) { return fmaxf(x, __shfl_xor(x, 32)); }
__device__ __forceinline__ float pair_sum(float x) { return x + __shfl_xor(x, 32); }

// async global->LDS, 16B per lane; lds base must be wave-uniform
__device__ __forceinline__ void gload16(const u16* g, u16* l) {
  __builtin_amdgcn_global_load_lds(
      (const __attribute__((address_space(1))) u32*)g,
      (__attribute__((address_space(3))) u32*)l, 16, 0, 0);
}

// ---------------------------------------------------------------------------
// f32 -> bf16 bulk convert (8 elements/thread)
// ---------------------------------------------------------------------------
__global__ __launch_bounds__(256) void cvt_bf16(
    const float* __restrict__ s, u16* __restrict__ d, int n)
{
  const int i = (blockIdx.x * 256 + threadIdx.x) * 8;
  if (i >= n) return;
  const float4 a = *(const float4*)&s[i];
  const float4 b = *(const float4*)&s[i + 4];
  union { u32 w[4]; uint4 u; } c;
  c.w[0] = packbf(a.x, a.y); c.w[1] = packbf(a.z, a.w);
  c.w[2] = packbf(b.x, b.y); c.w[3] = packbf(b.z, b.w);
  *(uint4*)&d[i] = c.u;
}

// ---------------------------------------------------------------------------
// Weight transpose + f32->bf16:  Wt[n][k] = bf16(W[k][n])
// ---------------------------------------------------------------------------
__global__ __launch_bounds__(256) void transpose_w(
    const float* __restrict__ W, u16* __restrict__ Wt, int K, int Nc)
{
  __shared__ float t[32][33];
  const int n0 = blockIdx.x * 32, k0 = blockIdx.y * 32;
  const int tx = threadIdx.x, ty = threadIdx.y;
#pragma unroll
  for (int i = 0; i < 4; ++i)
    t[ty + 8*i][tx] = W[(size_t)(k0 + ty + 8*i) * Nc + n0 + tx];
  __syncthreads();
#pragma unroll
  for (int i = 0; i < 4; ++i)
    Wt[(size_t)(n0 + ty + 8*i) * K + k0 + tx] = f2bf(t[tx][ty + 8*i]);
}

// ---------------------------------------------------------------------------
// V transpose: Vt[(b,h), d, key] = Vb[b, key, h*64 + d]   (Vb: [B,N2,1024])
// ---------------------------------------------------------------------------
__global__ __launch_bounds__(256) void transpose_v(
    const u16* __restrict__ Vb, u16* __restrict__ Vt)
{
  __shared__ u16 t[32][34];
  const int k0 = blockIdx.x * 32, d0 = blockIdx.y * 32, bh = blockIdx.z;
  const int b = bh >> 4, h = bh & 15;
  const int tx = threadIdx.x, ty = threadIdx.y;
#pragma unroll
  for (int i = 0; i < 4; ++i)
    t[ty + 8*i][tx] = Vb[((size_t)(b*N2_ + k0 + ty + 8*i))*1024 + h*64 + d0 + tx];
  __syncthreads();
#pragma unroll
  for (int i = 0; i < 4; ++i)
    Vt[((size_t)bh*64 + d0 + ty + 8*i)*N2_ + k0 + tx] = t[tx][ty + 8*i];
}

// ---------------------------------------------------------------------------
// GEMM  C = A[M][K](bf16) * Bt[N][K]^T (bf16):
// global_load_lds(16B) staging, BK=64, double-buffered LDS, one barrier/tile.
// LDS XOR chunk swizzle both-sides.  128x128 tile, 4 waves, 64x64/wave.
// ---------------------------------------------------------------------------
template<int OUT_BF16>
__global__ __launch_bounds__(256) void gemm_bt(
    const u16* __restrict__ A, const u16* __restrict__ Bt,
    float alpha, const float* __restrict__ bias,
    void* __restrict__ C0, void* __restrict__ C1, int Nout,
    int M, int K)
{
  __shared__ __align__(16) u16 As[2][128 * 64];
  __shared__ __align__(16) u16 Bs[2][128 * 64];
  const int tid = threadIdx.x;
  const int m0 = blockIdx.y * 128, n0 = blockIdx.x * 128;
  const int lane = tid & 63, wave = tid >> 6;
  const int wr = wave >> 1, wc = wave & 1;
  const int lr = lane & 15, lg = lane >> 4;
  f32x4 acc[4][4] = {};

  const int l8 = lane >> 3;
  const int c8 = ((lane & 7) ^ l8) * 8;
  const u16* ga = &A [(size_t)(m0 + 32*wave + l8) * K + c8];
  const u16* gb = &Bt[(size_t)(n0 + 32*wave + l8) * K + c8];

#define STAGE(buf, k0) { \
    _Pragma("unroll") \
    for (int i = 0; i < 4; ++i) { \
      gload16(ga + (size_t)(8*i)*K + (k0), &As[buf][(wave*4 + i) * 512]); \
      gload16(gb + (size_t)(8*i)*K + (k0), &Bs[buf][(wave*4 + i) * 512]); \
    } }

  STAGE(0, 0);
  __syncthreads();
  int cur = 0;
  const int NT = K >> 6;
  for (int t = 0; t < NT; ++t) {
    if (t + 1 < NT) STAGE(cur ^ 1, (t + 1) * 64);
#pragma unroll
    for (int kk = 0; kk < 2; ++kk) {
      bf16x8 af[4], bfr[4];
#pragma unroll
      for (int m = 0; m < 4; ++m) {
        const int row = wr*64 + m*16 + lr;
        af[m] = *(const bf16x8*)&As[cur][row*64 + (((kk*4 + lg) ^ (row & 7)) * 8)];
      }
#pragma unroll
      for (int n = 0; n < 4; ++n) {
        const int row = wc*64 + n*16 + lr;
        bfr[n] = *(const bf16x8*)&Bs[cur][row*64 + (((kk*4 + lg) ^ (row & 7)) * 8)];
      }
      __builtin_amdgcn_s_setprio(1);
#pragma unroll
      for (int m = 0; m < 4; ++m)
#pragma unroll
        for (int n = 0; n < 4; ++n)
          acc[m][n] = __builtin_amdgcn_mfma_f32_16x16x32_bf16(af[m], bfr[n], acc[m][n], 0, 0, 0);
      __builtin_amdgcn_s_setprio(0);
    }
    __syncthreads();
    cur ^= 1;
  }
#undef STAGE

  int cbase = n0;
  u16* Cb = (u16*)C0;
  if (OUT_BF16 && C1 && n0 >= Nout) { Cb = (u16*)C1; cbase = n0 - Nout; }

#pragma unroll
  for (int m = 0; m < 4; ++m)
#pragma unroll
    for (int n = 0; n < 4; ++n)
#pragma unroll
      for (int j = 0; j < 4; ++j) {
        const int r = m0 + wr*64 + m*16 + lg*4 + j;
        const int c = cbase + wc*64 + n*16 + lr;
        const float v = acc[m][n][j] * alpha;
        if (OUT_BF16) Cb[(size_t)r * Nout + c] = f2bf(v);
        else          ((float*)C0)[(size_t)r * Nout + c] = v + bias[c];
      }
}

// ---------------------------------------------------------------------------
// Flash attention, swapped-QK^T 32x32.
// This round: P stays fully in-register (pack + __shfl_xor(32) exchange +
// cndmask assembly — algebra verified against the R6-passing LDS layout);
// K/V double-buffered in LDS (ONE barrier/tile); 4-wave blocks (smaller
// barrier domain), grid (bh, 16 q-tiles of 128 rows).
// Q pre-scaled by SCALE*log2e.  Kb [B,N2,1024] bf16, Vt [B*H,64,N2] bf16.
// ---------------------------------------------------------------------------
#define QKSTEP(S, QF, KB) { \
    const int c_ = (((S)*2 + hi) ^ x7) * 8; \
    const bf16x8 ka_ = *(const bf16x8*)&KB[lq*64 + c_]; \
    const bf16x8 kb_ = *(const bf16x8*)&KB[(32+lq)*64 + c_]; \
    s0 = __builtin_amdgcn_mfma_f32_32x32x16_bf16(ka_, QF, s0, 0, 0, 0); \
    s1 = __builtin_amdgcn_mfma_f32_32x32x16_bf16(kb_, QF, s1, 0, 0, 0); }

__global__ __launch_bounds__(256, 4) void attn2(
    const u16* __restrict__ Q, const u16* __restrict__ Kb,
    const u16* __restrict__ Vt, const int* __restrict__ pad,
    u16* __restrict__ AO)
{
  const int bh = blockIdx.x, qt = blockIdx.y;
  const int b = bh >> 4, h = bh & 15;
  const int tid = threadIdx.x;
  const int wave = tid >> 6, lane = tid & 63;
  const int lq = lane & 31, hi = lane >> 5;
  const int x7 = lq & 7;

  __shared__ __align__(16) u16 Ks[2][64*64];
  __shared__ __align__(16) u16 Vs[2][64*64];
  __shared__ float bias[N2_];

  for (int i = tid; i < N2_; i += 256)
    bias[i] = pad[b*N2_ + i] ? 0.f : -30000.f;

  const int qrow = qt*128 + wave*32 + lq;
  const size_t qbase = ((size_t)b*N_ + qrow)*DIM_ + h*HD_;
  const bf16x8 qf0 = *(const bf16x8*)&Q[qbase +  0 + hi*8];
  const bf16x8 qf1 = *(const bf16x8*)&Q[qbase + 16 + hi*8];
  const bf16x8 qf2 = *(const bf16x8*)&Q[qbase + 32 + hi*8];
  const bf16x8 qf3 = *(const bf16x8*)&Q[qbase + 48 + hi*8];

  f32x16 o0 = {}, o1 = {};
  float mrun = -1e30f, lsum = 0.f;

  // staging: 256 thr cover rows {srow, srow+32} x 8 chunks; swz identical for
  // both rows ((srow+32)&7 == srow&7)
  const int srow = tid >> 3, schk = tid & 7;
  const int swz = (schk ^ (srow & 7)) * 8;
  const u16* kp = &Kb[(size_t)b*N2_*1024 + h*HD_ + (size_t)srow*1024 + schk*8];
  const u16* vp = &Vt[((size_t)bh*64 + srow)*N2_ + schk*8];

  uint4 kw0, kw1, vw0, vw1;
#define LREG(kt) { \
    kw0 = *(const uint4*)(kp + (size_t)(kt)*1024); \
    kw1 = *(const uint4*)(kp + (size_t)((kt)+32)*1024); \
    vw0 = *(const uint4*)(vp + (kt)); \
    vw1 = *(const uint4*)(vp + 32*N2_ + (kt)); }
#define WBUF(bf) { \
    *(uint4*)&Ks[bf][srow*64 + swz] = kw0; \
    *(uint4*)&Ks[bf][(srow+32)*64 + swz] = kw1; \
    *(uint4*)&Vs[bf][srow*64 + swz] = vw0; \
    *(uint4*)&Vs[bf][(srow+32)*64 + swz] = vw1; }

  LREG(0);
  WBUF(0);
  LREG(64);
  __syncthreads();          // buf0 + bias visible

  int cur = 0;
  for (int kt = 0; kt < N2_; kt += 64) {
    // write next tile into back buffer (safe: its old content was consumed
    // before the barrier that ended the previous iteration)
    if (kt + 64 < N2_)  WBUF(cur ^ 1);
    if (kt + 128 < N2_) LREG(kt + 128);

    // bias-init accs (mask folded into MFMA C-input)
    // C/D layout: col=lane&31 (query), key=(reg&3)+8*(reg>>2)+4*hi
    f32x16 s0, s1;
#pragma unroll
    for (int g = 0; g < 4; ++g) {
      const f32x4 b0 = *(const f32x4*)&bias[kt +      8*g + 4*hi];
      const f32x4 b1 = *(const f32x4*)&bias[kt + 32 + 8*g + 4*hi];
#pragma unroll
      for (int j = 0; j < 4; ++j) { s0[4*g+j] = b0[j]; s1[4*g+j] = b1[j]; }
    }

    __builtin_amdgcn_s_setprio(1);
    QKSTEP(0, qf0, Ks[cur]); QKSTEP(1, qf1, Ks[cur]);
    QKSTEP(2, qf2, Ks[cur]); QKSTEP(3, qf3, Ks[cur]);
    __builtin_amdgcn_s_setprio(0);

    // row max over this tile
    f32x16 mx;
#pragma unroll
    for (int r = 0; r < 16; ++r) mx[r] = fmaxf(s0[r], s1[r]);
#pragma unroll
    for (int d = 8; d >= 1; d >>= 1)
#pragma unroll
      for (int r = 0; r < 8; ++r) if (r < d) mx[r] = fmaxf(mx[r], mx[r + d]);
    const float tmax = pair_max(mx[0]);

    // defer-max (T13)
    if (!__all(tmax <= mrun + 8.f)) {
      const float mn = fmaxf(mrun, tmax);
      const float sc = exp2f(mrun - mn);
      mrun = mn;
      lsum *= sc;
#pragma unroll
      for (int r = 0; r < 16; ++r) { o0[r] *= sc; o1[r] *= sc; }
    }

    // P = exp2(S - m)
#pragma unroll
    for (int r = 0; r < 16; ++r) {
      s0[r] = exp2f(s0[r] - mrun);
      s1[r] = exp2f(s1[r] - mrun);
    }
    f32x16 sm;
#pragma unroll
    for (int r = 0; r < 16; ++r) sm[r] = s0[r] + s1[r];
#pragma unroll
    for (int d = 8; d >= 1; d >>= 1)
#pragma unroll
      for (int r = 0; r < 8; ++r) if (r < d) sm[r] += sm[r + d];
    lsum += pair_sum(sm[0]);

    // --- in-register P assembly ---
    // P-row word array W[0..31] (2 keys/word): own lane holds
    // r0[G]=W[4G+2hi], r1[G]=W[4G+2hi+1], G=0..7 (G<4 from s0, else s1).
    u32 r0[8], r1[8];
#pragma unroll
    for (int G = 0; G < 8; ++G) {
      const int gm = 4*(G & 3);
      if (G < 4) { r0[G] = packbf(s0[gm], s0[gm+1]); r1[G] = packbf(s0[gm+2], s0[gm+3]); }
      else       { r0[G] = packbf(s1[gm], s1[gm+1]); r1[G] = packbf(s1[gm+2], s1[gm+3]); }
    }
    // exchange with partner (lane^32): send the word the partner needs
    u32 rc0[4], rc1[4];
#pragma unroll
    for (int KS = 0; KS < 4; ++KS) {
      const u32 sa = hi ? r0[2*KS] : r0[2*KS+1];
      const u32 sb = hi ? r1[2*KS] : r1[2*KS+1];
      rc0[KS] = (u32)__shfl_xor((int)sa, 32);
      rc1[KS] = (u32)__shfl_xor((int)sb, 32);
    }

    // PV: frag(KS) = W[8KS+4hi .. +3]
    __builtin_amdgcn_s_setprio(1);
#pragma unroll
    for (int KS = 0; KS < 4; ++KS) {
      PU pu;
      pu.w[0] = hi ? rc0[KS]    : r0[2*KS];
      pu.w[1] = hi ? rc1[KS]    : r1[2*KS];
      pu.w[2] = hi ? r0[2*KS+1] : rc0[KS];
      pu.w[3] = hi ? r1[2*KS+1] : rc1[KS];
      const int c_ = ((KS*2 + hi) ^ x7) * 8;
      const bf16x8 va = *(const bf16x8*)&Vs[cur][lq*64 + c_];
      const bf16x8 vb = *(const bf16x8*)&Vs[cur][(32+lq)*64 + c_];
      o0 = __builtin_amdgcn_mfma_f32_32x32x16_bf16(va, pu.v, o0, 0, 0, 0);
      o1 = __builtin_amdgcn_mfma_f32_32x32x16_bf16(vb, pu.v, o1, 0, 0, 0);
    }
    __builtin_amdgcn_s_setprio(0);

    __syncthreads();          // all waves done with cur; back-buffer writes visible
    cur ^= 1;
  }
#undef LREG
#undef WBUF

  const float rls = 1.f / lsum;
  const size_t obase = ((size_t)b*N_ + qrow)*DIM_ + h*HD_;
#pragma unroll
  for (int g = 0; g < 4; ++g) {
    u32x2 w;
    w[0] = packbf(o0[4*g+0]*rls, o0[4*g+1]*rls);
    w[1] = packbf(o0[4*g+2]*rls, o0[4*g+3]*rls);
    *(u32x2*)&AO[obase + 8*g + 4*hi] = w;
    w[0] = packbf(o1[4*g+0]*rls, o1[4*g+1]*rls);
    w[1] = packbf(o1[4*g+2]*rls, o1[4*g+3]*rls);
    *(u32x2*)&AO[obase + 32 + 8*g + 4*hi] = w;
  }
}

// ---------------------------------------------------------------------------
extern "C" void kernel_launch(void* const* d_in, const int* in_sizes, int n_in,
                              void* d_out, int out_size, void* d_ws, size_t ws_size,
                              hipStream_t stream)
{
  const float* x     = (const float*)d_in[0];
  const float* y     = (const float*)d_in[1];
  const int*   pad   = (const int*)  d_in[2];
  const float* Wq    = (const float*)d_in[3];
  const float* Wkv   = (const float*)d_in[4];
  const float* Wproj = (const float*)d_in[5];
  const float* bproj = (const float*)d_in[6];

  // 56 MB workspace, lifetime-disjoint:
  //   [ 0,16) xb  t0->t3   then  Kb [0,8) t4->t6,  Vb [8,16) t4->t5
  //   [16,24) yb  t1->t4   then  Vtg [16,24) t5->t6
  //   [24,26) WqT t2->t3   [26,30) WkvT t2->t4   [30,32) WprojT t2->t7
  //   [32,48) Qb  t3->t6   [48,56) AOb t6->t7
  char* ws = (char*)d_ws;
  u16* xb     = (u16*)(ws);
  u16* Kb     = (u16*)(ws);
  u16* Vb     = (u16*)(ws + (size_t)( 8<<20));
  u16* yb     = (u16*)(ws + (size_t)(16<<20));
  u16* Vtg    = (u16*)(ws + (size_t)(16<<20));
  u16* WqT    = (u16*)(ws + (size_t)(24<<20));
  u16* WkvT   = (u16*)(ws + (size_t)(26<<20));
  u16* WprojT = (u16*)(ws + (size_t)(30<<20));
  u16* Qb     = (u16*)(ws + (size_t)(32<<20));
  u16* AOb    = (u16*)(ws + (size_t)(48<<20));

  const dim3 tb(32, 8);
  cvt_bf16<<<dim3(4096), 256, 0, stream>>>(x, xb, B_*N_*DIM_);
  cvt_bf16<<<dim3(2048), 256, 0, stream>>>(y, yb, B_*N2_*DIM_);
  transpose_w<<<dim3(32, 32), tb, 0, stream>>>(Wq,    WqT,    1024, 1024);
  transpose_w<<<dim3(64, 32), tb, 0, stream>>>(Wkv,   WkvT,   1024, 2048);
  transpose_w<<<dim3(32, 32), tb, 0, stream>>>(Wproj, WprojT, 1024, 1024);

  // Q = (x @ Wq) * SCALE*log2e
  gemm_bt<1><<<dim3( 8, 64), 256, 0, stream>>>(xb, WqT, SCALE_*LOG2E_, nullptr,
                                               Qb, nullptr, 1024, 8192, 1024);
  // [K|V] = y @ Wkv, split into Kb / Vb
  gemm_bt<1><<<dim3(16, 32), 256, 0, stream>>>(yb, WkvT, 1.0f, nullptr,
                                               Kb, Vb, 1024, 4096, 1024);
  transpose_v<<<dim3(32, 2, 64), tb, 0, stream>>>(Vb, Vtg);
  attn2<<<dim3(64, 16), 256, 0, stream>>>(Qb, Kb, Vtg, pad, AOb);
  // out = AO @ Wproj + bproj  (f32)
  gemm_bt<0><<<dim3( 8, 64), 256, 0, stream>>>(AOb, WprojT, 1.0f, bproj,
                                               d_out, nullptr, 1024, 8192, 1024);
}

// Round 10
// 173.761 us; speedup vs baseline: 1.0359x; 1.0359x over previous
//
#include <hip/hip_runtime.h>

typedef unsigned short u16;
typedef unsigned int   u32;
using bf16x8 = __bf16 __attribute__((ext_vector_type(8)));
using f32x4  = float  __attribute__((ext_vector_type(4)));
using f32x16 = float  __attribute__((ext_vector_type(16)));
using u32x2  = u32    __attribute__((ext_vector_type(2)));

#define B_    4
#define N_    2048
#define N2_   1024
#define DIM_  1024
#define H_    16
#define HD_   64
#define SCALE_ 0.125f
#define LOG2E_ 1.4426950408889634f

union PU { u32 w[4]; bf16x8 v; };

__device__ __forceinline__ u16 f2bf(float f) {
  unsigned u = __float_as_uint(f);
  u += 0x7fffu + ((u >> 16) & 1u);   // round-to-nearest-even
  return (u16)(u >> 16);
}

// compiler-generated bf16 pack (RNE) — layout-safe
__device__ __forceinline__ u32 packbf(float lo, float hi) {
  union { __bf16 b[2]; u32 u; } c;
  c.b[0] = (__bf16)lo; c.b[1] = (__bf16)hi;
  return c.u;
}

__device__ __forceinline__ float pair_max(float x) { return fmaxf(x, __shfl_xor(x, 32)); }
__device__ __forceinline__ float pair_sum(float x) { return x + __shfl_xor(x, 32); }

// async global->LDS, 16B per lane; lds base must be wave-uniform
__device__ __forceinline__ void gload16(const u16* g, u16* l) {
  __builtin_amdgcn_global_load_lds(
      (const __attribute__((address_space(1))) u32*)g,
      (__attribute__((address_space(3))) u32*)l, 16, 0, 0);
}

// ---------------------------------------------------------------------------
// f32 -> bf16 bulk convert (8 elements/thread)
// ---------------------------------------------------------------------------
__global__ __launch_bounds__(256) void cvt_bf16(
    const float* __restrict__ s, u16* __restrict__ d, int n)
{
  const int i = (blockIdx.x * 256 + threadIdx.x) * 8;
  if (i >= n) return;
  const float4 a = *(const float4*)&s[i];
  const float4 b = *(const float4*)&s[i + 4];
  union { u32 w[4]; uint4 u; } c;
  c.w[0] = packbf(a.x, a.y); c.w[1] = packbf(a.z, a.w);
  c.w[2] = packbf(b.x, b.y); c.w[3] = packbf(b.z, b.w);
  *(uint4*)&d[i] = c.u;
}

// ---------------------------------------------------------------------------
// Weight transpose + f32->bf16:  Wt[n][k] = bf16(W[k][n])
// ---------------------------------------------------------------------------
__global__ __launch_bounds__(256) void transpose_w(
    const float* __restrict__ W, u16* __restrict__ Wt, int K, int Nc)
{
  __shared__ float t[32][33];
  const int n0 = blockIdx.x * 32, k0 = blockIdx.y * 32;
  const int tx = threadIdx.x, ty = threadIdx.y;
#pragma unroll
  for (int i = 0; i < 4; ++i)
    t[ty + 8*i][tx] = W[(size_t)(k0 + ty + 8*i) * Nc + n0 + tx];
  __syncthreads();
#pragma unroll
  for (int i = 0; i < 4; ++i)
    Wt[(size_t)(n0 + ty + 8*i) * K + k0 + tx] = f2bf(t[tx][ty + 8*i]);
}

// ---------------------------------------------------------------------------
// V transpose: Vt[(b,h), d, key] = Vb[b, key, h*64 + d]   (Vb: [B,N2,1024])
// ---------------------------------------------------------------------------
__global__ __launch_bounds__(256) void transpose_v(
    const u16* __restrict__ Vb, u16* __restrict__ Vt)
{
  __shared__ u16 t[32][34];
  const int k0 = blockIdx.x * 32, d0 = blockIdx.y * 32, bh = blockIdx.z;
  const int b = bh >> 4, h = bh & 15;
  const int tx = threadIdx.x, ty = threadIdx.y;
#pragma unroll
  for (int i = 0; i < 4; ++i)
    t[ty + 8*i][tx] = Vb[((size_t)(b*N2_ + k0 + ty + 8*i))*1024 + h*64 + d0 + tx];
  __syncthreads();
#pragma unroll
  for (int i = 0; i < 4; ++i)
    Vt[((size_t)bh*64 + d0 + ty + 8*i)*N2_ + k0 + tx] = t[tx][ty + 8*i];
}

// ---------------------------------------------------------------------------
// GEMM  C = A[M][K](bf16) * Bt[N][K]^T (bf16):
// global_load_lds(16B) staging, BK=64, double-buffered LDS, one barrier/tile.
// LDS XOR chunk swizzle both-sides.  128x128 tile, 4 waves, 64x64/wave.
// ---------------------------------------------------------------------------
template<int OUT_BF16>
__global__ __launch_bounds__(256) void gemm_bt(
    const u16* __restrict__ A, const u16* __restrict__ Bt,
    float alpha, const float* __restrict__ bias,
    void* __restrict__ C0, void* __restrict__ C1, int Nout,
    int M, int K)
{
  __shared__ __align__(16) u16 As[2][128 * 64];
  __shared__ __align__(16) u16 Bs[2][128 * 64];
  const int tid = threadIdx.x;
  const int m0 = blockIdx.y * 128, n0 = blockIdx.x * 128;
  const int lane = tid & 63, wave = tid >> 6;
  const int wr = wave >> 1, wc = wave & 1;
  const int lr = lane & 15, lg = lane >> 4;
  f32x4 acc[4][4] = {};

  const int l8 = lane >> 3;
  const int c8 = ((lane & 7) ^ l8) * 8;
  const u16* ga = &A [(size_t)(m0 + 32*wave + l8) * K + c8];
  const u16* gb = &Bt[(size_t)(n0 + 32*wave + l8) * K + c8];

#define STAGE(buf, k0) { \
    _Pragma("unroll") \
    for (int i = 0; i < 4; ++i) { \
      gload16(ga + (size_t)(8*i)*K + (k0), &As[buf][(wave*4 + i) * 512]); \
      gload16(gb + (size_t)(8*i)*K + (k0), &Bs[buf][(wave*4 + i) * 512]); \
    } }

  STAGE(0, 0);
  __syncthreads();
  int cur = 0;
  const int NT = K >> 6;
  for (int t = 0; t < NT; ++t) {
    if (t + 1 < NT) STAGE(cur ^ 1, (t + 1) * 64);
#pragma unroll
    for (int kk = 0; kk < 2; ++kk) {
      bf16x8 af[4], bfr[4];
#pragma unroll
      for (int m = 0; m < 4; ++m) {
        const int row = wr*64 + m*16 + lr;
        af[m] = *(const bf16x8*)&As[cur][row*64 + (((kk*4 + lg) ^ (row & 7)) * 8)];
      }
#pragma unroll
      for (int n = 0; n < 4; ++n) {
        const int row = wc*64 + n*16 + lr;
        bfr[n] = *(const bf16x8*)&Bs[cur][row*64 + (((kk*4 + lg) ^ (row & 7)) * 8)];
      }
      __builtin_amdgcn_s_setprio(1);
#pragma unroll
      for (int m = 0; m < 4; ++m)
#pragma unroll
        for (int n = 0; n < 4; ++n)
          acc[m][n] = __builtin_amdgcn_mfma_f32_16x16x32_bf16(af[m], bfr[n], acc[m][n], 0, 0, 0);
      __builtin_amdgcn_s_setprio(0);
    }
    __syncthreads();
    cur ^= 1;
  }
#undef STAGE

  int cbase = n0;
  u16* Cb = (u16*)C0;
  if (OUT_BF16 && C1 && n0 >= Nout) { Cb = (u16*)C1; cbase = n0 - Nout; }

#pragma unroll
  for (int m = 0; m < 4; ++m)
#pragma unroll
    for (int n = 0; n < 4; ++n)
#pragma unroll
      for (int j = 0; j < 4; ++j) {
        const int r = m0 + wr*64 + m*16 + lg*4 + j;
        const int c = cbase + wc*64 + n*16 + lr;
        const float v = acc[m][n][j] * alpha;
        if (OUT_BF16) Cb[(size_t)r * Nout + c] = f2bf(v);
        else          ((float*)C0)[(size_t)r * Nout + c] = v + bias[c];
      }
}

// ---------------------------------------------------------------------------
// Flash attention, swapped-QK^T 32x32 (R8 structure: 8 waves x 32 q-rows,
// LDS P roundtrip) + K/V DOUBLE-buffer (ONE barrier/tile, reg-prefetch of
// next tile under compute) + Ps stride 37 (bank-conflict-free: gcd(5,32)=1).
// Q pre-scaled by SCALE*log2e.  Kb [B,N2,1024] bf16, Vt [B*H,64,N2] bf16.
// blockIdx.x = bh (XCD locality), .y = qt.
// ---------------------------------------------------------------------------
#define QKSTEP(S, QF, KB) { \
    const int c_ = (((S)*2 + hi) ^ x7) * 8; \
    const bf16x8 ka_ = *(const bf16x8*)&KB[lq*64 + c_]; \
    const bf16x8 kb_ = *(const bf16x8*)&KB[(32+lq)*64 + c_]; \
    s0 = __builtin_amdgcn_mfma_f32_32x32x16_bf16(ka_, QF, s0, 0, 0, 0); \
    s1 = __builtin_amdgcn_mfma_f32_32x32x16_bf16(kb_, QF, s1, 0, 0, 0); }

__global__ __launch_bounds__(512, 4) void attn2(
    const u16* __restrict__ Q, const u16* __restrict__ Kb,
    const u16* __restrict__ Vt, const int* __restrict__ pad,
    u16* __restrict__ AO)
{
  const int bh = blockIdx.x, qt = blockIdx.y;
  const int b = bh >> 4, h = bh & 15;
  const int tid = threadIdx.x;
  const int wave = tid >> 6, lane = tid & 63;
  const int lq = lane & 31, hi = lane >> 5;
  const int x7 = lq & 7;

  __shared__ __align__(16) u16 Ks[2][64*64];
  __shared__ __align__(16) u16 Vs[2][64*64];
  __shared__ __align__(16) u32 Ps[8][32][37];   // stride 37: conflict-free
  __shared__ float bias[N2_];

  for (int i = tid; i < N2_; i += 512)
    bias[i] = pad[b*N2_ + i] ? 0.f : -30000.f;

  const int qrow = qt*256 + wave*32 + lq;
  const size_t qbase = ((size_t)b*N_ + qrow)*DIM_ + h*HD_;
  const bf16x8 qf0 = *(const bf16x8*)&Q[qbase +  0 + hi*8];
  const bf16x8 qf1 = *(const bf16x8*)&Q[qbase + 16 + hi*8];
  const bf16x8 qf2 = *(const bf16x8*)&Q[qbase + 32 + hi*8];
  const bf16x8 qf3 = *(const bf16x8*)&Q[qbase + 48 + hi*8];

  f32x16 o0 = {}, o1 = {};
  float mrun = -1e30f, lsum = 0.f;

  // staging: 512 thr cover 64 rows x 8 chunks (one uint4 each)
  const int srow = tid >> 3, schk = tid & 7;
  const int swz = (schk ^ (srow & 7)) * 8;
  const u16* kp = &Kb[(size_t)b*N2_*1024 + h*HD_ + (size_t)srow*1024 + schk*8];
  const u16* vp = &Vt[((size_t)bh*64 + srow)*N2_ + schk*8];
  u32 (*pw)[37] = Ps[wave];

  uint4 kw, vw;
#define LREG(kt) { \
    kw = *(const uint4*)(kp + (size_t)(kt)*1024); \
    vw = *(const uint4*)(vp + (kt)); }
#define WBUF(bf) { \
    *(uint4*)&Ks[bf][srow*64 + swz] = kw; \
    *(uint4*)&Vs[bf][srow*64 + swz] = vw; }

  LREG(0);
  WBUF(0);
  LREG(64);
  __syncthreads();          // buf0 + bias visible

  int cur = 0;
  for (int kt = 0; kt < N2_; kt += 64) {
    // back-buffer fill (its readers passed the barrier ending iter kt-1)
    if (kt + 64 < N2_)  WBUF(cur ^ 1);
    if (kt + 128 < N2_) LREG(kt + 128);

    // bias-init accs (mask folded into MFMA C-input)
    // C/D layout: col=lane&31 (query), key=(reg&3)+8*(reg>>2)+4*hi
    f32x16 s0, s1;
#pragma unroll
    for (int g = 0; g < 4; ++g) {
      const f32x4 b0 = *(const f32x4*)&bias[kt +      8*g + 4*hi];
      const f32x4 b1 = *(const f32x4*)&bias[kt + 32 + 8*g + 4*hi];
#pragma unroll
      for (int j = 0; j < 4; ++j) { s0[4*g+j] = b0[j]; s1[4*g+j] = b1[j]; }
    }

    __builtin_amdgcn_s_setprio(1);
    QKSTEP(0, qf0, Ks[cur]); QKSTEP(1, qf1, Ks[cur]);
    QKSTEP(2, qf2, Ks[cur]); QKSTEP(3, qf3, Ks[cur]);
    __builtin_amdgcn_s_setprio(0);

    // row max over this tile
    f32x16 mx;
#pragma unroll
    for (int r = 0; r < 16; ++r) mx[r] = fmaxf(s0[r], s1[r]);
#pragma unroll
    for (int d = 8; d >= 1; d >>= 1)
#pragma unroll
      for (int r = 0; r < 8; ++r) if (r < d) mx[r] = fmaxf(mx[r], mx[r + d]);
    const float tmax = pair_max(mx[0]);

    // defer-max (T13)
    if (!__all(tmax <= mrun + 8.f)) {
      const float mn = fmaxf(mrun, tmax);
      const float sc = exp2f(mrun - mn);
      mrun = mn;
      lsum *= sc;
#pragma unroll
      for (int r = 0; r < 16; ++r) { o0[r] *= sc; o1[r] *= sc; }
    }

    // P = exp2(S - m)
#pragma unroll
    for (int r = 0; r < 16; ++r) {
      s0[r] = exp2f(s0[r] - mrun);
      s1[r] = exp2f(s1[r] - mrun);
    }
    f32x16 sm;
#pragma unroll
    for (int r = 0; r < 16; ++r) sm[r] = s0[r] + s1[r];
#pragma unroll
    for (int d = 8; d >= 1; d >>= 1)
#pragma unroll
      for (int r = 0; r < 8; ++r) if (r < d) sm[r] += sm[r + d];
    lsum += pair_sum(sm[0]);

    // P -> per-wave LDS (u32 both sides, same-wave RAW, no barrier)
#pragma unroll
    for (int g = 0; g < 4; ++g) {
      pw[lq][     4*g + 2*hi    ] = packbf(s0[4*g+0], s0[4*g+1]);
      pw[lq][     4*g + 2*hi + 1] = packbf(s0[4*g+2], s0[4*g+3]);
      pw[lq][16 + 4*g + 2*hi    ] = packbf(s1[4*g+0], s1[4*g+1]);
      pw[lq][16 + 4*g + 2*hi + 1] = packbf(s1[4*g+2], s1[4*g+3]);
    }
    asm volatile("" ::: "memory");

    // PV
    __builtin_amdgcn_s_setprio(1);
#pragma unroll
    for (int KS = 0; KS < 4; ++KS) {
      PU pu;
#pragma unroll
      for (int j = 0; j < 4; ++j) pu.w[j] = pw[lq][KS*8 + 4*hi + j];
      const int c_ = ((KS*2 + hi) ^ x7) * 8;
      const bf16x8 va = *(const bf16x8*)&Vs[cur][lq*64 + c_];
      const bf16x8 vb = *(const bf16x8*)&Vs[cur][(32+lq)*64 + c_];
      o0 = __builtin_amdgcn_mfma_f32_32x32x16_bf16(va, pu.v, o0, 0, 0, 0);
      o1 = __builtin_amdgcn_mfma_f32_32x32x16_bf16(vb, pu.v, o1, 0, 0, 0);
    }
    __builtin_amdgcn_s_setprio(0);

    __syncthreads();        // cur consumed by all waves; back-buffer visible
    cur ^= 1;
  }
#undef LREG
#undef WBUF

  const float rls = 1.f / lsum;
  const size_t obase = ((size_t)b*N_ + qrow)*DIM_ + h*HD_;
#pragma unroll
  for (int g = 0; g < 4; ++g) {
    u32x2 w;
    w[0] = packbf(o0[4*g+0]*rls, o0[4*g+1]*rls);
    w[1] = packbf(o0[4*g+2]*rls, o0[4*g+3]*rls);
    *(u32x2*)&AO[obase + 8*g + 4*hi] = w;
    w[0] = packbf(o1[4*g+0]*rls, o1[4*g+1]*rls);
    w[1] = packbf(o1[4*g+2]*rls, o1[4*g+3]*rls);
    *(u32x2*)&AO[obase + 32 + 8*g + 4*hi] = w;
  }
}

// ---------------------------------------------------------------------------
extern "C" void kernel_launch(void* const* d_in, const int* in_sizes, int n_in,
                              void* d_out, int out_size, void* d_ws, size_t ws_size,
                              hipStream_t stream)
{
  const float* x     = (const float*)d_in[0];
  const float* y     = (const float*)d_in[1];
  const int*   pad   = (const int*)  d_in[2];
  const float* Wq    = (const float*)d_in[3];
  const float* Wkv   = (const float*)d_in[4];
  const float* Wproj = (const float*)d_in[5];
  const float* bproj = (const float*)d_in[6];

  // 56 MB workspace, lifetime-disjoint:
  //   [ 0,16) xb  t0->t3   then  Kb [0,8) t4->t6,  Vb [8,16) t4->t5
  //   [16,24) yb  t1->t4   then  Vtg [16,24) t5->t6
  //   [24,26) WqT t2->t3   [26,30) WkvT t2->t4   [30,32) WprojT t2->t7
  //   [32,48) Qb  t3->t6   [48,56) AOb t6->t7
  char* ws = (char*)d_ws;
  u16* xb     = (u16*)(ws);
  u16* Kb     = (u16*)(ws);
  u16* Vb     = (u16*)(ws + (size_t)( 8<<20));
  u16* yb     = (u16*)(ws + (size_t)(16<<20));
  u16* Vtg    = (u16*)(ws + (size_t)(16<<20));
  u16* WqT    = (u16*)(ws + (size_t)(24<<20));
  u16* WkvT   = (u16*)(ws + (size_t)(26<<20));
  u16* WprojT = (u16*)(ws + (size_t)(30<<20));
  u16* Qb     = (u16*)(ws + (size_t)(32<<20));
  u16* AOb    = (u16*)(ws + (size_t)(48<<20));

  const dim3 tb(32, 8);
  cvt_bf16<<<dim3(4096), 256, 0, stream>>>(x, xb, B_*N_*DIM_);
  cvt_bf16<<<dim3(2048), 256, 0, stream>>>(y, yb, B_*N2_*DIM_);
  transpose_w<<<dim3(32, 32), tb, 0, stream>>>(Wq,    WqT,    1024, 1024);
  transpose_w<<<dim3(64, 32), tb, 0, stream>>>(Wkv,   WkvT,   1024, 2048);
  transpose_w<<<dim3(32, 32), tb, 0, stream>>>(Wproj, WprojT, 1024, 1024);

  // Q = (x @ Wq) * SCALE*log2e
  gemm_bt<1><<<dim3( 8, 64), 256, 0, stream>>>(xb, WqT, SCALE_*LOG2E_, nullptr,
                                               Qb, nullptr, 1024, 8192, 1024);
  // [K|V] = y @ Wkv, split into Kb / Vb
  gemm_bt<1><<<dim3(16, 32), 256, 0, stream>>>(yb, WkvT, 1.0f, nullptr,
                                               Kb, Vb, 1024, 4096, 1024);
  transpose_v<<<dim3(32, 2, 64), tb, 0, stream>>>(Vb, Vtg);
  attn2<<<dim3(64, 8), 512, 0, stream>>>(Qb, Kb, Vtg, pad, AOb);
  // out = AO @ Wproj + bproj  (f32)
  gemm_bt<0><<<dim3( 8, 64), 256, 0, stream>>>(AOb, WprojT, 1.0f, bproj,
                                               d_out, nullptr, 1024, 8192, 1024);
}